// Round 1
// 108.509 us; speedup vs baseline: 1.0646x; 1.0646x over previous
//
#include <hip/hip_runtime.h>

typedef _Float16 half8  __attribute__((ext_vector_type(8)));
typedef __fp16   fp16x2 __attribute__((ext_vector_type(2)));   // cvt_pkrtz native type
typedef float    floatx4 __attribute__((ext_vector_type(4)));

#define IMG_H 64
#define IMG_W 64
#define TH 16
#define TW 32
#define INW 40            // staged cols: tx0-4 .. tx0+35
#define H1W 34            // h1 cols: tx0-1 .. tx0+32
#define NPX 640           // padded plane (40 tiles x 16 px; p in [612,640) = write-only pad)
#define CP 912            // f16 elems per copy; stride 456 dwords ≡ 8 mod 32 banks
#define CPM1 911          // copy stride for linearized addressing: off = c*CPM1 + (lin1+4)

__device__ __forceinline__ unsigned pk2u(float a, float b) {
    fp16x2 h = __builtin_amdgcn_cvt_pkrtz(a, b);
    return __builtin_bit_cast(unsigned, h);
}

__global__ __launch_bounds__(256, 8) void pixelcnn_mfma10(
    const float* __restrict__ x,
    const float* __restrict__ w1, const float* __restrict__ b1,
    const float* __restrict__ w2, const float* __restrict__ b2,
    const float* __restrict__ w3, const float* __restrict__ b3,
    float* __restrict__ out)
{
    // LDS: 7296 + 1024 + 1536 + 196 + 10240 = 20292 B -> 8 blocks/CU (8*20480 = 160 KiB exact)
    __shared__ __align__(16) _Float16      s16[4 * CP];     // input tile f16, 4 shifted copies
    __shared__ __align__(16) _Float16      s_w1t[16 * 32];  // [ch][k] f16, k=(kr=q)*8+(kc=j)
    __shared__ __align__(16) unsigned char s_w2t8[16 * 96]; // [ch][k] fp8 e4m3, k=tap*16+ic
    __shared__ __align__(16) float         s_b1[16], s_b2[16], s_w3[16];
    __shared__ float                       s_b3;
    __shared__ __align__(16) unsigned      s_h1[2 * NPX * 2]; // fp8 h1: [c2][px][8ch] 8B/px/plane

    const int t    = threadIdx.x;
    const int lane = t & 63;
    const int wave = t >> 6;
    const int n    = lane & 15;   // MFMA: weight-row ch field & B-col pixel field
    const int quad = lane >> 4;   // MFMA k-slice group / D-row quad
    const int img  = blockIdx.y;
    const int btile = blockIdx.x;
    const int ty0 = (btile >> 1) * TH;
    const int tx0 = (btile & 1) * TW;

    const float* xim = x + img * (IMG_H * IMG_W);

    // ------- Phase 0: stage input as f16 x4 shifted copies + weights -------
    // Copy c holds col X at elem c*CP + (4-c) + lin(X)  ==  c*CPM1 + 4 + lin(X).
    // (copy 0 shifted +4 vs the old layout so the reader's offset is linear in c;
    //  alignment: (4-c)+px ≡ 0 mod 4 when px≡c mod 4; bank stagger 8c unchanged)
    if (t < 210) {
        int r = t / 10, c4 = (t - r * 10) * 4;
        int gy = ty0 - 4 + r;
        int gx0 = tx0 - 4 + c4;                 // multiple of 4
        float4 v  = {0.f, 0.f, 0.f, 0.f};
        float4 v2 = {0.f, 0.f, 0.f, 0.f};
        if ((unsigned)gy < IMG_H) {
            const float* rp = xim + gy * IMG_W;
            if ((unsigned)gx0 < IMG_W)       v  = *(const float4*)(rp + gx0);
            if ((unsigned)(gx0 + 4) < IMG_W) v2 = *(const float4*)(rp + gx0 + 4);
        }
        unsigned a0 = pk2u(v.x,  v.y),  a1 = pk2u(v.z,  v.w);
        unsigned a2 = pk2u(v2.x, v2.y), a3 = pk2u(v2.z, v2.w);
        unsigned m10 = (a0 >> 16) | (a1 << 16);   // elems 1,2
        unsigned m21 = (a1 >> 16) | (a2 << 16);   // elems 3,4
        unsigned m32 = (a2 >> 16) | (a3 << 16);   // elems 5,6
        int lin = r * INW + c4;
        *(uint2*)&s16[0*CP + 4 + lin + 0] = uint2{a0,  a1 };  // cols c4..c4+3
        *(uint2*)&s16[1*CP + 3 + lin + 1] = uint2{m10, m21};  // cols c4+1..c4+4
        *(uint2*)&s16[2*CP + 2 + lin + 2] = uint2{a1,  a2 };  // cols c4+2..c4+5
        *(uint2*)&s16[3*CP + 1 + lin + 3] = uint2{m21, m32};  // cols c4+3..c4+6
    }
    // Zero the tail sliver each copy can read past staged content (rel. elems
    // 840..887 cover all real and dummy fragment over-reads).
    if (t < 192) {
        int c = t / 48, e = t - c * 48;
        s16[c * CP + (4 - c) + 840 + e] = (_Float16)0.f;
    }
    {
        int ch = t >> 4, l = t & 15;         // 256 threads = 16 ch x 16 lanes
        const float* w1c = w1 + ch * 49;
#pragma unroll
        for (int j2 = 0; j2 < 2; ++j2) {     // w1t: k = q*8+j <-> tap (kr=q, kc=j)
            int k = l + 16 * j2, q = k >> 3, jj = k & 7;
            float v = 0.f;
            if (q < 3)      { if (jj < 7) v = w1c[q * 7 + jj]; }
            else            { if (jj < 3) v = w1c[21 + jj];    }
            s_w1t[ch * 32 + k] = (_Float16)v;
        }
        const float* w2cl = w2 + (ch * 16 + l) * 9;   // w2t8: k = tap*16 + ic(=l), fp8 e4m3
#pragma unroll
        for (int j = 0; j < 6; ++j) {
            float v = (j < 5) ? w2cl[j] : 0.f;
            unsigned q8 = (unsigned)__builtin_amdgcn_cvt_pk_fp8_f32(v, 0.f, 0, false);
            s_w2t8[ch * 96 + j * 16 + l] = (unsigned char)(q8 & 0xff);
        }
    }
    if (t < 16) { s_b1[t] = b1[t]; s_b2[t] = b2[t]; s_w3[t] = w3[t]; }
    if (t == 16) s_b3 = b3[0];
    __syncthreads();

    // ------- Phase 1: L1 7x7 via f16 MFMA; unconditional store (border fixed later) -------
    {
        const half8 afrag = *(const half8*)&s_w1t[n * 32 + quad * 8];
        const floatx4 bias1 = ((const floatx4*)s_b1)[quad];
        int p  = wave * 16 + n;               // p < 64
        int py = (p >= H1W) ? 1 : 0;
        int px = p - py * H1W;
        int lin1p = (py + quad) * INW + px + 4;   // +4: linearized copy base
        unsigned wd = (unsigned)((quad >> 1) * (NPX * 2) + p * 2 + (quad & 1)); // dword idx

#pragma unroll
        for (int i = 0; i < 10; ++i) {        // tiles wave, wave+4, ..., wave+36 (pad tiles dummy)
            int c = px & 3;
            const _Float16* ap = &s16[c * CPM1 + lin1p];
            uint2 lo = *(const uint2*)ap;         // elems px..px+3 (8B aligned)
            uint2 hi = *(const uint2*)(ap + 4);   // elems px+4..px+7
            uint4 bu; bu.x = lo.x; bu.y = lo.y; bu.z = hi.x; bu.w = hi.y;
            half8 b = __builtin_bit_cast(half8, bu);
            floatx4 acc = bias1;
            acc = __builtin_amdgcn_mfma_f32_16x16x32_f16(afrag, b, acc, 0, 0, 0);
            // D: row = ch = quad*4+r, col = px = n -> 4 ch as 4 fp8 bytes = one b32
            int d = __builtin_amdgcn_cvt_pk_fp8_f32(fmaxf(acc[0], 0.f), fmaxf(acc[1], 0.f), 0, false);
            d = __builtin_amdgcn_cvt_pk_fp8_f32(fmaxf(acc[2], 0.f), fmaxf(acc[3], 0.f), d, true);
            s_h1[wd] = (unsigned)d;
            // branchless advance by 64 pixels: py += 1 (+wrap), px += 30
            int px2 = px + 30;
            bool wrap = px2 >= H1W;
            px     = wrap ? px2 - H1W : px2;
            lin1p += wrap ? 76 : 70;
            wd    += 128;
        }
    }
    __syncthreads();

    // ------- Phase 1.5: zero the out-of-image h1 border cells phase 2 reads -------
    // Reads span h1 rows 0..16 and cols 0..33. Out-of-image among those:
    //   ty0==0  -> row 0 (all 34 cols);  tx0==0 -> col 0;  tx0==32 -> col 33.
    // (row 17 / pad region are never read -> no need to zero.)
    {
        int cell = -1;
        if (t < 34)      { if (ty0 == 0) cell = t; }
        else if (t < 52) { cell = (t - 34) * H1W + ((tx0 == 0) ? 0 : 33); }
        if (cell >= 0) {
            *(uint2*)&s_h1[cell * 2]           = uint2{0u, 0u};
            *(uint2*)&s_h1[NPX * 2 + cell * 2] = uint2{0u, 0u};
        }
    }
    __syncthreads();

    // ------- Phase 2: L2 3x3 via fp8 MFMA + fused relu/w3-dot/sigmoid/store -------
    {
        const long w2f0 = *(const long*)&s_w2t8[n * 96 +  0 + quad * 8];
        const long w2f1 = *(const long*)&s_w2t8[n * 96 + 32 + quad * 8];
        const long w2f2 = *(const long*)&s_w2t8[n * 96 + 64 + quad * 8];
        const floatx4 bias2 = ((const floatx4*)s_b2)[quad];
        const floatx4 w3q   = ((const floatx4*)s_w3)[quad];
        const float bias3 = s_b3;
        const int y0 = wave >> 1, x0 = (wave & 1) * 16;  // wave -> (row parity, col half)
        const int tqh = quad >> 1, plane = quad & 1;
        const int E0 = (y0 + 1) * H1W + x0 + n + 1;      // lane pixel in h1 coords (k=0)
        // taps: f0 -> {(-1,-1),(-1,0)}, f1 -> {(-1,1),(0,-1)}, f2 -> {(0,0), pad(A=0)}
        const char* h1b = (const char*)s_h1 + plane * (NPX * 8);
        const char* a0 = h1b + (E0 - 35 + tqh) * 8;
        const char* a1 = h1b + (E0 + (tqh ? -1 : -33)) * 8;
        const char* a2 = h1b + E0 * 8;                   // tqh=1 reads real px (zero A-side)
        // lane (n, quad) stores row ty0 + y0 + 2*(g*4+quad), col tx0 + x0 + n
        float* sbase = out + ((img * IMG_H) + ty0 + y0 + 2 * quad) * IMG_W + tx0 + x0 + n;

#pragma unroll
        for (int g = 0; g < 2; ++g) {                    // 2 groups of 4 rows
            float sv0, sv1, sv2, sv3;
#pragma unroll
            for (int q = 0; q < 4; ++q) {                // k = g*4+q; dE=68 px -> 544 B imm
                const int k = g * 4 + q;
                floatx4 acc = bias2;
                acc = __builtin_amdgcn_mfma_f32_16x16x32_fp8_fp8(w2f0, *(const long*)(a0 + k * 544), acc, 0, 0, 0);
                acc = __builtin_amdgcn_mfma_f32_16x16x32_fp8_fp8(w2f1, *(const long*)(a1 + k * 544), acc, 0, 0, 0);
                acc = __builtin_amdgcn_mfma_f32_16x16x32_fp8_fp8(w2f2, *(const long*)(a2 + k * 544), acc, 0, 0, 0);
                float s = fmaxf(acc[0], 0.f) * w3q[0];
                s = fmaf(fmaxf(acc[1], 0.f), w3q[1], s);
                s = fmaf(fmaxf(acc[2], 0.f), w3q[2], s);
                s = fmaf(fmaxf(acc[3], 0.f), w3q[3], s);
                s += __shfl_xor(s, 16);
                s += __shfl_xor(s, 32);                  // full 16-ch sum, replicated in all quads
                if      (q == 0) sv0 = s;
                else if (q == 1) sv1 = s;
                else if (q == 2) sv2 = s;
                else             sv3 = s;
            }
            // each lane picks the k matching its quad -> full-wave sigmoid + unmasked store
            float t01 = (quad & 1) ? sv1 : sv0;
            float t23 = (quad & 1) ? sv3 : sv2;
            float v   = (quad & 2) ? t23 : t01;
            float r = __builtin_amdgcn_rcpf(1.f + __expf(-(v + bias3)));
            *(float*)((char*)sbase + g * 2048) = r;      // +8 rows per group
        }
    }
}

extern "C" void kernel_launch(void* const* d_in, const int* in_sizes, int n_in,
                              void* d_out, int out_size, void* d_ws, size_t ws_size,
                              hipStream_t stream) {
    const float* x  = (const float*)d_in[0];
    const float* w1 = (const float*)d_in[1];
    const float* b1 = (const float*)d_in[2];
    const float* w2 = (const float*)d_in[3];
    const float* b2 = (const float*)d_in[4];
    const float* w3 = (const float*)d_in[5];
    const float* b3 = (const float*)d_in[6];
    float* out = (float*)d_out;

    dim3 grid(8, 1024);   // 2x4 tiles per image, 1024 images
    dim3 block(256);
    hipLaunchKernelGGL(pixelcnn_mfma10, grid, block, 0, stream,
                       x, w1, b1, w2, b2, w3, b3, out);
}

// Round 2
// 105.069 us; speedup vs baseline: 1.0995x; 1.0327x over previous
//
#include <hip/hip_runtime.h>

typedef _Float16 half8  __attribute__((ext_vector_type(8)));
typedef __fp16   fp16x2 __attribute__((ext_vector_type(2)));   // cvt_pkrtz native type
typedef float    floatx4 __attribute__((ext_vector_type(4)));

#define IMG_H 64
#define IMG_W 64
#define TH 8              // rows per block; block covers full image width (64 cols)
#define INW 72            // staged cols: img cols -4 .. 67 (zeros outside 0..63)
#define INH 12            // staged rows: img rows ty0-4 .. ty0+7 (zeros outside image)
#define H1W 66            // h1 cols 0..65 = img cols -1..64 (cols 0 and 65 always zero)
#define H1H 9             // h1 rows 0..8  = img rows ty0-1 .. ty0+7
#define PLDW (H1H*H1W*2)  // dwords per h1 plane = 1188
#define CP 912            // f16 elems per staged copy; 456 dw stride ≡ 8 mod 32 banks
#define CPM1 911          // reader: elem off = c*CPM1 + 4 + S   (S = staged col)

__device__ __forceinline__ unsigned pk2u(float a, float b) {
    fp16x2 h = __builtin_amdgcn_cvt_pkrtz(a, b);
    return __builtin_bit_cast(unsigned, h);
}

__global__ __launch_bounds__(256, 8) void pixelcnn_mfma11(
    const float* __restrict__ x,
    const float* __restrict__ w1, const float* __restrict__ b1,
    const float* __restrict__ w2, const float* __restrict__ b2,
    const float* __restrict__ w3, const float* __restrict__ b3,
    float* __restrict__ out)
{
    // LDS: 7296 + 1024 + 1536 + 196 + 9504 = 19556 B -> 8 blocks/CU
    __shared__ __align__(16) _Float16      s16[4 * CP];     // input strip f16, 4 shifted copies
    __shared__ __align__(16) _Float16      s_w1t[16 * 32];  // [ch][k] f16, k=(kr=q)*8+(kc=j)
    __shared__ __align__(16) unsigned char s_w2t8[16 * 96]; // [ch][k] fp8 e4m3, k=tap*16+ic
    __shared__ __align__(16) float         s_b1[16], s_b2[16], s_w3[16];
    __shared__ float                       s_b3;
    __shared__ __align__(16) unsigned      s_h1[2 * PLDW];  // fp8 h1: [plane][px][4ch] 2dw/px/plane

    const int t    = threadIdx.x;
    const int lane = t & 63;
    const int wave = t >> 6;
    const int n    = lane & 15;   // MFMA: weight-row ch field & B-col pixel field
    const int quad = lane >> 4;   // MFMA k-slice group / D-row quad
    const int img  = blockIdx.y;
    const int ty0  = blockIdx.x * TH;

    const float* xim = x + img * (IMG_H * IMG_W);

    // ------- Phase 0: stage input strip as f16 x4 shifted copies + weights -------
    // Copy c stores staged col X (= img col X-4) of row r at elem c*CP + (4-c) + r*INW + X.
    // All four writes land at c*CP + 4 + lin (lin = r*INW + c4). OOB loads stage zeros.
    if (t < 216) {
        int r = t / 18, c4 = (t - r * 18) * 4;
        int gy = ty0 - 4 + r;
        int gx0 = c4 - 4;                       // img col, multiple of 4
        float4 v  = {0.f, 0.f, 0.f, 0.f};
        float4 v2 = {0.f, 0.f, 0.f, 0.f};
        if ((unsigned)gy < IMG_H) {
            const float* rp = xim + gy * IMG_W;
            if ((unsigned)gx0 < IMG_W)       v  = *(const float4*)(rp + gx0);
            if ((unsigned)(gx0 + 4) < IMG_W) v2 = *(const float4*)(rp + gx0 + 4);
        }
        unsigned a0 = pk2u(v.x,  v.y),  a1 = pk2u(v.z,  v.w);
        unsigned a2 = pk2u(v2.x, v2.y), a3 = pk2u(v2.z, v2.w);
        unsigned m10 = (a0 >> 16) | (a1 << 16);   // elems 1,2
        unsigned m21 = (a1 >> 16) | (a2 << 16);   // elems 3,4
        unsigned m32 = (a2 >> 16) | (a3 << 16);   // elems 5,6
        int lin = r * INW + c4;
        *(uint2*)&s16[0*CP + 4 + lin] = uint2{a0,  a1 };  // cols c4..c4+3
        *(uint2*)&s16[1*CP + 4 + lin] = uint2{m10, m21};  // cols c4+1..c4+4
        *(uint2*)&s16[2*CP + 4 + lin] = uint2{a1,  a2 };  // cols c4+2..c4+5
        *(uint2*)&s16[3*CP + 4 + lin] = uint2{m21, m32};  // cols c4+3..c4+6
    } else if (t < 234) {
        // zero h1 border cols 0 and 65 (img cols -1, 64 -> always out of image);
        // phase 1 never writes these cells, phase 2 reads them.
        int idx = t - 216;                       // 18 cells: 9 rows x {0,65}
        int cell = (idx >> 1) * H1W + ((idx & 1) ? 65 : 0);
        *(uint2*)&s_h1[cell * 2]        = uint2{0u, 0u};
        *(uint2*)&s_h1[PLDW + cell * 2] = uint2{0u, 0u};
    }
    {
        int ch = t >> 4, l = t & 15;         // 256 threads = 16 ch x 16 lanes
        const float* w1c = w1 + ch * 49;
#pragma unroll
        for (int j2 = 0; j2 < 2; ++j2) {     // w1t: k = q*8+j <-> tap (kr=q, kc=j)
            int k = l + 16 * j2, q = k >> 3, jj = k & 7;
            float v = 0.f;
            if (q < 3)      { if (jj < 7) v = w1c[q * 7 + jj]; }
            else            { if (jj < 3) v = w1c[21 + jj];    }
            s_w1t[ch * 32 + k] = (_Float16)v;
        }
        const float* w2cl = w2 + (ch * 16 + l) * 9;   // w2t8: k = tap*16 + ic(=l), fp8 e4m3
#pragma unroll
        for (int j = 0; j < 6; ++j) {
            float v = (j < 5) ? w2cl[j] : 0.f;
            unsigned q8 = (unsigned)__builtin_amdgcn_cvt_pk_fp8_f32(v, 0.f, 0, false);
            s_w2t8[ch * 96 + j * 16 + l] = (unsigned char)(q8 & 0xff);
        }
    }
    if (t < 16) { s_b1[t] = b1[t]; s_b2[t] = b2[t]; s_w3[t] = w3[t]; }
    if (t == 16) s_b3 = b3[0];
    __syncthreads();

    // ------- Phase 1: L1 7x7 via f16 MFMA; fixed column per lane, rows advance -------
    // Lane owns img col px = wave*16+n (0..63); h1 col px+1. 9 rows, fully affine:
    // all LDS addresses are base + compile-time immediates.
    {
        const half8 afrag = *(const half8*)&s_w1t[n * 32 + quad * 8];
        const floatx4 bias1 = ((const floatx4*)s_b1)[quad];
        const int px = wave * 16 + n;             // img col, 0..63
        const int S  = px + 1;                    // staged read start col (= img col px-3)
        const int c  = S & 3;                     // copy index: FIXED per lane
        const _Float16* ap0 = &s16[c * CPM1 + 4 + S + quad * INW];
        const unsigned wd0 = (unsigned)((quad >> 1) * PLDW + S * 2 + (quad & 1)); // dword idx
        const bool top = (ty0 == 0);

#pragma unroll
        for (int i = 0; i < H1H; ++i) {           // h1 row i = img row ty0-1+i
            const _Float16* ap = ap0 + i * INW;
            uint2 lo = *(const uint2*)ap;         // staged cols S..S+3
            uint2 hi = *(const uint2*)(ap + 4);   // staged cols S+4..S+7
            uint4 bu; bu.x = lo.x; bu.y = lo.y; bu.z = hi.x; bu.w = hi.y;
            half8 b = __builtin_bit_cast(half8, bu);
            floatx4 acc = bias1;
            acc = __builtin_amdgcn_mfma_f32_16x16x32_f16(afrag, b, acc, 0, 0, 0);
            // D: row = ch = quad*4+r, col = px = n -> 4 ch as 4 fp8 bytes = one b32
            int d = __builtin_amdgcn_cvt_pk_fp8_f32(fmaxf(acc[0], 0.f), fmaxf(acc[1], 0.f), 0, false);
            d = __builtin_amdgcn_cvt_pk_fp8_f32(fmaxf(acc[2], 0.f), fmaxf(acc[3], 0.f), d, true);
            unsigned dv = (unsigned)d;
            if (i == 0) dv = top ? 0u : dv;       // h1 row 0 = img row -1 for top strip
            s_h1[wd0 + i * (H1W * 2)] = dv;
        }
    }
    __syncthreads();

    // ------- Phase 2: L2 3x3 via fp8 MFMA + fused relu/w3-dot/sigmoid/store -------
    {
        const long w2f0 = *(const long*)&s_w2t8[n * 96 +  0 + quad * 8];
        const long w2f1 = *(const long*)&s_w2t8[n * 96 + 32 + quad * 8];
        const long w2f2 = *(const long*)&s_w2t8[n * 96 + 64 + quad * 8];
        const floatx4 bias2 = ((const floatx4*)s_b2)[quad];
        const floatx4 w3q   = ((const floatx4*)s_w3)[quad];
        const float bias3 = s_b3;
        const int x0 = wave * 16;                        // wave -> col quarter
        const int tqh = quad >> 1, plane = quad & 1;
        const int E0 = H1W + x0 + n + 1;                 // lane pixel, out row ty0+0 (h1 row 1)
        // taps: f0 -> {(-1,-1),(-1,0)}, f1 -> {(-1,1),(0,-1)}, f2 -> {(0,0), pad(A=0)}
        const char* h1b = (const char*)s_h1 + plane * (PLDW * 4);
        const char* a0 = h1b + (E0 - H1W - 1 + tqh) * 8;
        const char* a1 = h1b + (E0 + (tqh ? -1 : -(H1W - 1))) * 8;
        const char* a2 = h1b + E0 * 8;                   // tqh=1 reads real px (zero A-side)
        // lane (n, quad) stores row ty0 + g*4 + quad, col x0 + n
        float* sbase = out + ((img * IMG_H) + ty0 + quad) * IMG_W + x0 + n;

#pragma unroll
        for (int g = 0; g < 2; ++g) {                    // 2 groups of 4 rows
            float sv0, sv1, sv2, sv3;
#pragma unroll
            for (int q = 0; q < 4; ++q) {                // k = g*4+q; row step = 66 px = 528 B
                const int k = g * 4 + q;
                floatx4 acc = bias2;
                acc = __builtin_amdgcn_mfma_f32_16x16x32_fp8_fp8(w2f0, *(const long*)(a0 + k * 528), acc, 0, 0, 0);
                acc = __builtin_amdgcn_mfma_f32_16x16x32_fp8_fp8(w2f1, *(const long*)(a1 + k * 528), acc, 0, 0, 0);
                acc = __builtin_amdgcn_mfma_f32_16x16x32_fp8_fp8(w2f2, *(const long*)(a2 + k * 528), acc, 0, 0, 0);
                float s = fmaxf(acc[0], 0.f) * w3q[0];
                s = fmaf(fmaxf(acc[1], 0.f), w3q[1], s);
                s = fmaf(fmaxf(acc[2], 0.f), w3q[2], s);
                s = fmaf(fmaxf(acc[3], 0.f), w3q[3], s);
                s += __shfl_xor(s, 16);
                s += __shfl_xor(s, 32);                  // full 16-ch sum, replicated in all quads
                if      (q == 0) sv0 = s;
                else if (q == 1) sv1 = s;
                else if (q == 2) sv2 = s;
                else             sv3 = s;
            }
            // each lane picks the k matching its quad -> full-wave sigmoid + unmasked store
            float t01 = (quad & 1) ? sv1 : sv0;
            float t23 = (quad & 1) ? sv3 : sv2;
            float v   = (quad & 2) ? t23 : t01;
            float r = __builtin_amdgcn_rcpf(1.f + __expf(-(v + bias3)));
            *(float*)((char*)sbase + g * 1024) = r;      // +4 rows per group
        }
    }
}

extern "C" void kernel_launch(void* const* d_in, const int* in_sizes, int n_in,
                              void* d_out, int out_size, void* d_ws, size_t ws_size,
                              hipStream_t stream) {
    const float* x  = (const float*)d_in[0];
    const float* w1 = (const float*)d_in[1];
    const float* b1 = (const float*)d_in[2];
    const float* w2 = (const float*)d_in[3];
    const float* b2 = (const float*)d_in[4];
    const float* w3 = (const float*)d_in[5];
    const float* b3 = (const float*)d_in[6];
    float* out = (float*)d_out;

    dim3 grid(8, 1024);   // 8 row-strips per image, 1024 images
    dim3 block(256);
    hipLaunchKernelGGL(pixelcnn_mfma11, grid, block, 0, stream,
                       x, w1, b1, w2, b2, w3, b3, out);
}

// Round 4
// 101.244 us; speedup vs baseline: 1.1410x; 1.0378x over previous
//
#include <hip/hip_runtime.h>

typedef _Float16 half8  __attribute__((ext_vector_type(8)));
typedef __fp16   fp16x2 __attribute__((ext_vector_type(2)));   // cvt_pkrtz native type
typedef float    floatx4 __attribute__((ext_vector_type(4)));
typedef float    f4a __attribute__((ext_vector_type(4), aligned(4)));  // 4B-aligned float4 load

#define IMG_H 64
#define IMG_W 64
#define TH 16             // rows per block (two 8-row strips); full image width
#define INW 72            // staged cols: img cols -4 .. 67 (zeros outside 0..63)
#define H1W 66            // h1 cols 0..65 = img cols -1..64 (cols 0 and 65 always zero)
#define H1H 17            // h1 rows 0..16 = img rows ty0-1 .. ty0+15
#define PLDW (H1H*H1W*2)  // dwords per h1 plane = 2244
#define CP 1440           // f16 elems per staged copy (20 rows x 72)
#define CPM1 1439         // reader: elem off = c*CPM1 + 4 + S + row*INW
#define S16N (4*CP + 4)   // +4: copy-3 tail spill pad

__device__ __forceinline__ unsigned pk2u(float a, float b) {
    fp16x2 h = __builtin_amdgcn_cvt_pkrtz(a, b);
    return __builtin_bit_cast(unsigned, h);
}

__global__ __launch_bounds__(512, 8) void pixelcnn_mfma12(
    const float* __restrict__ x,
    const float* __restrict__ w1, const float* __restrict__ b1,
    const float* __restrict__ w2, const float* __restrict__ b2,
    const float* __restrict__ w3, const float* __restrict__ b3,
    float* __restrict__ out)
{
    // LDS: 11528 + 1536 + 17952 = 31016 B -> 4 blocks/CU x 8 waves = 32 waves/CU (full)
    __shared__ __align__(16) _Float16      s16[S16N];      // input strip f16, 4 shifted copies
    __shared__ __align__(16) unsigned char s_w2t8[16 * 96];// [ch][k] fp8 e4m3, k=tap*16+ic
    __shared__ __align__(16) unsigned      s_h1[2 * PLDW]; // fp8 h1: [plane][px][8ch] 8B/px/plane

    const int t    = threadIdx.x;
    const int lane = t & 63;
    const int wave = t >> 6;
    const int n    = lane & 15;   // MFMA: weight-row ch field & B-col pixel field
    const int quad = lane >> 4;   // MFMA k-slice group / D-row quad
    const int s    = wave >> 2;   // strip (0: rows ty0..+7, 1: rows ty0+8..+15)
    const int x0q  = wave & 3;    // col quarter
    const int img  = blockIdx.y;
    const int ty0  = blockIdx.x * TH;

    const float* xim = x + img * (IMG_H * IMG_W);

    // ------- Per-lane weights/biases DIRECT from global (L2-hot, 3KB total) -------
    // A-frag: w1[n][kr=quad][kc=j], j<7 (quad<3) / j<3 (quad==3); RTE casts match old path.
    const float* wr = w1 + n * 49 + quad * 7;
    f4a wlo = *(const f4a*)wr;          // kc 0..3   (4B-aligned load)
    f4a whi = *(const f4a*)(wr + 3);    // kc 3..6   (max idx 762 < 784: in-bounds)
    const floatx4 bias1 = *(const floatx4*)(b1 + quad * 4);
    const floatx4 bias2 = *(const floatx4*)(b2 + quad * 4);
    const floatx4 w3q   = *(const floatx4*)(w3 + quad * 4);
    const float   bias3 = b3[0];
    half8 af;
    {
        bool q3 = (quad == 3);
        af[0] = (_Float16)wlo[0];
        af[1] = (_Float16)wlo[1];
        af[2] = (_Float16)wlo[2];
        af[3] = (_Float16)(q3 ? 0.f : wlo[3]);
        af[4] = (_Float16)(q3 ? 0.f : whi[1]);
        af[5] = (_Float16)(q3 ? 0.f : whi[2]);
        af[6] = (_Float16)(q3 ? 0.f : whi[3]);
        af[7] = (_Float16)0.f;
    }

    // ------- Phase 0: stage 20-row input strip as f16 x4 shifted copies -------
    // Copy c stores col X of row r at elem c*CP + 4 + r*INW + (X - c); reader uses
    // E = c*CPM1 + 4 + S + row*INW (E ≡ 0 mod 4 since S ≡ c mod 4). OOB loads -> zeros.
    if (t < 360) {
        int r = t / 18, c4 = (t - r * 18) * 4;
        int gy = ty0 - 4 + r;
        int gx0 = c4 - 4;                       // img col, multiple of 4
        float4 v  = {0.f, 0.f, 0.f, 0.f};
        float4 v2 = {0.f, 0.f, 0.f, 0.f};
        if ((unsigned)gy < IMG_H) {
            const float* rp = xim + gy * IMG_W;
            if ((unsigned)gx0 < IMG_W)       v  = *(const float4*)(rp + gx0);
            if ((unsigned)(gx0 + 4) < IMG_W) v2 = *(const float4*)(rp + gx0 + 4);
        }
        unsigned a0 = pk2u(v.x,  v.y),  a1 = pk2u(v.z,  v.w);
        unsigned a2 = pk2u(v2.x, v2.y), a3 = pk2u(v2.z, v2.w);
        unsigned m10 = (a0 >> 16) | (a1 << 16);   // elems 1,2
        unsigned m21 = (a1 >> 16) | (a2 << 16);   // elems 3,4
        unsigned m32 = (a2 >> 16) | (a3 << 16);   // elems 5,6
        int lin = r * INW + c4;
        *(uint2*)&s16[0*CP + 4 + lin] = uint2{a0,  a1 };  // cols c4..c4+3
        *(uint2*)&s16[1*CP + 4 + lin] = uint2{m10, m21};  // cols c4+1..c4+4
        *(uint2*)&s16[2*CP + 4 + lin] = uint2{a1,  a2 };  // cols c4+2..c4+5
        *(uint2*)&s16[3*CP + 4 + lin] = uint2{m21, m32};  // cols c4+3..c4+6
    } else if (t < 394) {
        // zero h1 border cols 0 and 65 (img cols -1, 64 -> always out of image);
        // phase 1 never writes these cells, phase 2 reads them. 17 rows x {0,65}.
        int idx = t - 360;
        int cell = (idx >> 1) * H1W + ((idx & 1) ? 65 : 0);
        *(uint2*)&s_h1[cell * 2]        = uint2{0u, 0u};
        *(uint2*)&s_h1[PLDW + cell * 2] = uint2{0u, 0u};
    }
    if (t >= 256) {
        // w2t8: k = tap*16 + ic, fp8 e4m3 -- 256 threads = 16 ch x 16 ic
        int ch = (t >> 4) & 15, l = t & 15;
        const float* w2cl = w2 + (ch * 16 + l) * 9;
#pragma unroll
        for (int j = 0; j < 6; ++j) {
            float v = (j < 5) ? w2cl[j] : 0.f;
            unsigned q8 = (unsigned)__builtin_amdgcn_cvt_pk_fp8_f32(v, 0.f, 0, false);
            s_w2t8[ch * 96 + j * 16 + l] = (unsigned char)(q8 & 0xff);
        }
    }
    __syncthreads();

    // ------- Phase 1: L1 7x7 via f16 MFMA; fixed column per lane, rows advance -------
    // Wave (s, x0q): h1 rows s*8 .. s*8+8, cols x0q*16+1 .. +16. Strip 1 skips its
    // i=0 (row 8) -- strip 0's i=8 computes the identical value.
    {
        const int px = x0q * 16 + n;              // img col, 0..63
        const int S  = px + 1;                    // staged read start col
        const int c  = S & 3;                     // copy index: fixed per lane
        const _Float16* ap0 = &s16[c * CPM1 + 4 + S + (s * 8 + quad) * INW];
        const unsigned wd0 = (unsigned)((quad >> 1) * PLDW + ((s * 8) * H1W + S) * 2 + (quad & 1));
        const bool top = (ty0 == 0) && (s == 0);

#pragma unroll
        for (int i = 0; i < 9; ++i) {             // h1 row s*8+i = img row ty0-1+s*8+i
            if (i == 0 && s != 0) continue;       // row 8 owned by strip 0
            const _Float16* ap = ap0 + i * INW;
            uint2 lo = *(const uint2*)ap;         // staged cols S..S+3 (8B aligned)
            uint2 hi = *(const uint2*)(ap + 4);   // staged cols S+4..S+7
            uint4 bu; bu.x = lo.x; bu.y = lo.y; bu.z = hi.x; bu.w = hi.y;
            half8 b = __builtin_bit_cast(half8, bu);
            floatx4 acc = bias1;
            acc = __builtin_amdgcn_mfma_f32_16x16x32_f16(af, b, acc, 0, 0, 0);
            // D: row = ch = quad*4+r, col = px = n -> 4 ch as 4 fp8 bytes = one b32
            int d = __builtin_amdgcn_cvt_pk_fp8_f32(fmaxf(acc[0], 0.f), fmaxf(acc[1], 0.f), 0, false);
            d = __builtin_amdgcn_cvt_pk_fp8_f32(fmaxf(acc[2], 0.f), fmaxf(acc[3], 0.f), d, true);
            unsigned dv = (unsigned)d;
            if (i == 0 && top) dv = 0u;           // h1 row 0 = img row -1 for top block
            s_h1[wd0 + i * (H1W * 2)] = dv;
        }
    }
    __syncthreads();

    // ------- Phase 2: L2 3x3 via fp8 MFMA + fused relu/w3-dot/sigmoid/store -------
    {
        const long w2f0 = *(const long*)&s_w2t8[n * 96 +  0 + quad * 8];
        const long w2f1 = *(const long*)&s_w2t8[n * 96 + 32 + quad * 8];
        const long w2f2 = *(const long*)&s_w2t8[n * 96 + 64 + quad * 8];
        const int x0 = x0q * 16;
        const int tqh = quad >> 1, plane = quad & 1;
        const int E0 = (s * 8 + 1) * H1W + x0 + n + 1;   // lane pixel, out row ty0+s*8 (k=0)
        // taps: f0 -> {(-1,-1),(-1,0)}, f1 -> {(-1,1),(0,-1)}, f2 -> {(0,0), pad(A=0)}
        const char* h1b = (const char*)s_h1 + plane * (PLDW * 4);
        const char* a0 = h1b + (E0 - H1W - 1 + tqh) * 8;
        const char* a1 = h1b + (E0 + (tqh ? -1 : -(H1W - 1))) * 8;
        const char* a2 = h1b + E0 * 8;                   // tqh=1 reads real px (zero A-side)
        // lane (n, quad) stores row ty0 + s*8 + g*4 + quad, col x0 + n
        float* sbase = out + ((img * IMG_H) + ty0 + s * 8 + quad) * IMG_W + x0 + n;

#pragma unroll
        for (int g = 0; g < 2; ++g) {                    // 2 groups of 4 rows
            float sv0, sv1, sv2, sv3;
#pragma unroll
            for (int q = 0; q < 4; ++q) {                // k = g*4+q; row step = 66 px = 528 B
                const int k = g * 4 + q;
                floatx4 acc = bias2;
                acc = __builtin_amdgcn_mfma_f32_16x16x32_fp8_fp8(w2f0, *(const long*)(a0 + k * 528), acc, 0, 0, 0);
                acc = __builtin_amdgcn_mfma_f32_16x16x32_fp8_fp8(w2f1, *(const long*)(a1 + k * 528), acc, 0, 0, 0);
                acc = __builtin_amdgcn_mfma_f32_16x16x32_fp8_fp8(w2f2, *(const long*)(a2 + k * 528), acc, 0, 0, 0);
                float sacc = fmaxf(acc[0], 0.f) * w3q[0];
                sacc = fmaf(fmaxf(acc[1], 0.f), w3q[1], sacc);
                sacc = fmaf(fmaxf(acc[2], 0.f), w3q[2], sacc);
                sacc = fmaf(fmaxf(acc[3], 0.f), w3q[3], sacc);
                sacc += __shfl_xor(sacc, 16);
                sacc += __shfl_xor(sacc, 32);            // full 16-ch sum, replicated in all quads
                if      (q == 0) sv0 = sacc;
                else if (q == 1) sv1 = sacc;
                else if (q == 2) sv2 = sacc;
                else             sv3 = sacc;
            }
            // each lane picks the k matching its quad -> full-wave sigmoid + unmasked store
            float t01 = (quad & 1) ? sv1 : sv0;
            float t23 = (quad & 1) ? sv3 : sv2;
            float v   = (quad & 2) ? t23 : t01;
            float r = __builtin_amdgcn_rcpf(1.f + __expf(-(v + bias3)));
            *(float*)((char*)sbase + g * 1024) = r;      // +4 rows per group
        }
    }
}

extern "C" void kernel_launch(void* const* d_in, const int* in_sizes, int n_in,
                              void* d_out, int out_size, void* d_ws, size_t ws_size,
                              hipStream_t stream) {
    const float* x  = (const float*)d_in[0];
    const float* w1 = (const float*)d_in[1];
    const float* b1 = (const float*)d_in[2];
    const float* w2 = (const float*)d_in[3];
    const float* b2 = (const float*)d_in[4];
    const float* w3 = (const float*)d_in[5];
    const float* b3 = (const float*)d_in[6];
    float* out = (float*)d_out;

    dim3 grid(4, 1024);   // 4 16-row strips per image, 1024 images
    dim3 block(512);
    hipLaunchKernelGGL(pixelcnn_mfma12, grid, block, 0, stream,
                       x, w1, b1, w2, b2, w3, b3, out);
}